// Round 3
// baseline (394.516 us; speedup 1.0000x reference)
//
#include <hip/hip_runtime.h>
#include <stdint.h>

#define S_LEN 256
#define DIM   128
#define EPSL  1e-5f
#define NCORE 64

typedef __bf16 bf16x8 __attribute__((ext_vector_type(8)));
typedef float  f32x4  __attribute__((ext_vector_type(4)));

__device__ __forceinline__ unsigned short f2bf_bits(float f) {
  union { float f; unsigned int u; } v; v.f = f;
  unsigned int r = v.u + 0x7fffu + ((v.u >> 16) & 1u);   // RTNE (weights/init)
  return (unsigned short)(r >> 16);
}
__device__ __forceinline__ unsigned f2bf_rhu(float f) {
  return (__float_as_uint(f) + 0x8000u) >> 16;
}
__device__ __forceinline__ unsigned pack_rhu(float lo, float hi) {
  return __builtin_amdgcn_perm(__float_as_uint(hi) + 0x8000u,
                               __float_as_uint(lo) + 0x8000u, 0x07060302u);
}
// tanh(x) = 1 - 2/(e^{2x}+1): ~1e-6 rel err, exact at +-inf.
__device__ __forceinline__ float tanh_fast(float x) {
  float e = __expf(2.f * x);
  return 1.f - 2.f * __builtin_amdgcn_rcpf(e + 1.f);
}

template<int CTRL>
__device__ __forceinline__ float dpp_rot_add(float v) {
  int r = __builtin_amdgcn_update_dpp(0, __float_as_int(v), CTRL, 0xF, 0xF, true);
  return v + __int_as_float(r);
}
template<int CTRL>
__device__ __forceinline__ float dpp_rot_max(float v) {
  int r = __builtin_amdgcn_update_dpp(0, __float_as_int(v), CTRL, 0xF, 0xF, true);
  return fmaxf(v, __int_as_float(r));
}
__device__ __forceinline__ float dpp_sum16(float v) {
  v = dpp_rot_add<0x124>(v); v = dpp_rot_add<0x128>(v);
  v = dpp_rot_add<0x39>(v);  v = dpp_rot_add<0x4E>(v);
  return v;
}
__device__ __forceinline__ float dpp_max16(float v) {
  v = dpp_rot_max<0x124>(v); v = dpp_rot_max<0x128>(v);
  v = dpp_rot_max<0x39>(v);  v = dpp_rot_max<0x4E>(v);
  return v;
}
template<int CTRL>
__device__ __forceinline__ void red_level7(float& s, float& sq, float* d) {
  s  = dpp_rot_add<CTRL>(s);
  sq = dpp_rot_add<CTRL>(sq);
#pragma unroll
  for (int j = 0; j < 5; j++) d[j] = dpp_rot_add<CTRL>(d[j]);
}
template<int JJ>
__device__ __forceinline__ float bcast16(float v) {
  int r = __builtin_amdgcn_ds_swizzle(__float_as_int(v), (JJ << 5) | 0x10);
  return __int_as_float(r);
}

union Frag8 { unsigned short us[8]; bf16x8 v; int4 i4; };

// ================= rnn_fused: 2-wave core blocks, minimal sync domain ======
// Core blocks (0..63): ONE 16-row slab per block, TWO waves (1 per SIMD, no
// issue dilation). Wave uw owns h-dims [uw*64, uw*64+64): 16 serial MFMAs per
// step (4 independent 2+2 chains), tanh x16, swizzled h_bf dbuf write, one
// cheap 2-wave barrier per step. The SAME waves produce xp[t'] = bias +
// e[t']@Wih (f32, bit-identical to R0/R2 numerics) 4-5 steps ahead through a
// 6-entry f32 LDS ring: one t' per wave per step-pair, e-gather issued one
// pair (~1400cy) ahead, xid one pair before that. hout staging reads the
// PREVIOUS step's h buffer (off the pre-barrier critical tail); chunk flags
// therefore publish one step later (chunk c at t=32(c+1), chunk 7 in
// epilogue). Tail blocks (64..191): 8 rows each, 4 rows/wave, same LN1 ->
// proj -> 5-dim RNN2 -> LN2 -> pool -> softmax pipeline as before.
__global__ __launch_bounds__(128, 1)
void rnn_fused(const int* __restrict__ x, const float* __restrict__ emb,
               const float* __restrict__ Wih1, const float* __restrict__ bih1,
               const float* __restrict__ Whh1, const float* __restrict__ bhh1,
               const float* __restrict__ g1, const float* __restrict__ be1,
               const float* __restrict__ Wih2, const float* __restrict__ bih2,
               const float* __restrict__ Whh2, const float* __restrict__ bhh2,
               const float* __restrict__ g2, const float* __restrict__ be2,
               unsigned short* __restrict__ hout, int* flags,
               float* __restrict__ out)
{
  __shared__ __align__(16) float xp_ring[6][8][64][4];         // 48 KB f32 xp
  __shared__ __align__(16) unsigned short h_bf[2][16 * 128];   // 8 KB dbuf
  __shared__ __align__(16) float p_lds[2][4][32][8];           // 8 KB (tail)

  const int tid  = threadIdx.x;
  const int uw   = tid >> 6;          // wave id (0,1) — uniform per wave
  const int lane = tid & 63;
  const int l15  = lane & 15;
  const int q    = lane >> 4;

  if (blockIdx.x < NCORE) {
    // ========================= CORE ROLE =========================
    const int r0u = blockIdx.x * 16;
    for (int i = tid; i < 16 * 128; i += 128) h_bf[1][i] = 0;  // h_{-1} = 0

    // ---- weights: Whh half (own 64 dims) + Wih full (for xp production) ----
    bf16x8 whh[4][4]; bf16x8 wih[8][4]; float biasx[8];
#pragma unroll
    for (int n = 0; n < 4; n++) {
      int d = uw * 64 + n * 16 + l15;
#pragma unroll
      for (int kt = 0; kt < 4; kt++) {
        Frag8 f;
#pragma unroll
        for (int j = 0; j < 8; j++)
          f.us[j] = f2bf_bits(Whh1[d * DIM + kt * 32 + q * 8 + j]);
        whh[n][kt] = f.v;
      }
    }
#pragma unroll
    for (int n8 = 0; n8 < 8; n8++) {
      int d = n8 * 16 + l15;
      biasx[n8] = bih1[d] + bhh1[d];
#pragma unroll
      for (int kt = 0; kt < 4; kt++) {
        Frag8 f;
#pragma unroll
        for (int j = 0; j < 8; j++)
          f.us[j] = f2bf_bits(Wih1[d * DIM + kt * 32 + q * 8 + j]);
        wih[n8][kt] = f.v;
      }
    }

    float4 eld[8];            // staged e row (f32) for the pending xp tile
    int xid_pref = 0;

    auto gather = [&](int tq) {
      int xid = x[(size_t)(r0u + l15) * S_LEN + tq];
      const float* pe = emb + (size_t)xid * DIM + q * 8;
#pragma unroll
      for (int kt = 0; kt < 4; kt++) {
        eld[kt * 2]     = *(const float4*)(pe + kt * 32);
        eld[kt * 2 + 1] = *(const float4*)(pe + kt * 32 + 4);
      }
    };
    auto produce = [&](int entry) {     // xp tile from staged eld -> ring
      Frag8 af[4];
#pragma unroll
      for (int kt = 0; kt < 4; kt++) {
        af[kt].i4.x = (int)pack_rhu(eld[kt * 2].x,     eld[kt * 2].y);
        af[kt].i4.y = (int)pack_rhu(eld[kt * 2].z,     eld[kt * 2].w);
        af[kt].i4.z = (int)pack_rhu(eld[kt * 2 + 1].x, eld[kt * 2 + 1].y);
        af[kt].i4.w = (int)pack_rhu(eld[kt * 2 + 1].z, eld[kt * 2 + 1].w);
      }
#pragma unroll
      for (int n8 = 0; n8 < 8; n8++) {
        f32x4 a = {biasx[n8], biasx[n8], biasx[n8], biasx[n8]};
#pragma unroll
        for (int kt = 0; kt < 4; kt++)
          a = __builtin_amdgcn_mfma_f32_16x16x32_bf16(af[kt].v, wih[n8][kt], a, 0, 0, 0);
        *(f32x4*)&xp_ring[entry][n8][lane][0] = a;
      }
    };
    auto serial_step = [&](int T, int RM) {
      const int rb = (T + 1) & 1, wb = T & 1;
      f32x4 xpv[4];
#pragma unroll
      for (int n = 0; n < 4; n++)
        xpv[n] = *(const f32x4*)&xp_ring[RM][uw * 4 + n][lane][0];
      bf16x8 a0 = *(const bf16x8*)&h_bf[rb][l15 * 128 + ((( 0 + q) ^ l15) & 15) * 8];
      bf16x8 a1 = *(const bf16x8*)&h_bf[rb][l15 * 128 + ((( 4 + q) ^ l15) & 15) * 8];
      bf16x8 a2 = *(const bf16x8*)&h_bf[rb][l15 * 128 + ((( 8 + q) ^ l15) & 15) * 8];
      bf16x8 a3 = *(const bf16x8*)&h_bf[rb][l15 * 128 + (((12 + q) ^ l15) & 15) * 8];
#pragma unroll
      for (int n = 0; n < 4; n++) {
        f32x4 acc = xpv[n]; f32x4 accb = {0.f, 0.f, 0.f, 0.f};
        acc  = __builtin_amdgcn_mfma_f32_16x16x32_bf16(a0, whh[n][0], acc,  0, 0, 0);
        accb = __builtin_amdgcn_mfma_f32_16x16x32_bf16(a2, whh[n][2], accb, 0, 0, 0);
        acc  = __builtin_amdgcn_mfma_f32_16x16x32_bf16(a1, whh[n][1], acc,  0, 0, 0);
        accb = __builtin_amdgcn_mfma_f32_16x16x32_bf16(a3, whh[n][3], accb, 0, 0, 0);
        acc += accb;
        const int c = uw * 64 + n * 16 + l15, oct = c >> 3;
#pragma unroll
        for (int r = 0; r < 4; r++) {   // D-layout: row = q*4+r, col = c
          int row = q * 4 + r;
          h_bf[wb][row * 128 + ((oct ^ row) & 15) * 8 + (c & 7)] =
              (unsigned short)f2bf_rhu(tanh_fast(acc[r]));
        }
      }
    };
    auto readback = [&](int T) {        // own-half h(T) -> hout (deferred)
      const int hb_ = T & 1;
#pragma unroll
      for (int i = 0; i < 2; i++) {
        int row = i * 8 + (lane >> 3), ol = uw * 8 + (lane & 7);
        int4 v = *(const int4*)&h_bf[hb_][row * 128 + ((ol ^ row) & 15) * 8];
        *(int4*)(hout + ((size_t)(r0u + row) * S_LEN + T) * DIM + ol * 8) = v;
      }
    };

    // ---- prologue: ring entries {uw, 2+uw}; stage loads for 4+uw; xid 6+uw
    gather(uw);      produce(uw);
    gather(2 + uw);  produce(2 + uw);
    gather(4 + uw);
    xid_pref = x[(size_t)(r0u + l15) * S_LEN + 6 + uw];
    int em = 4 + uw;                    // next ring entry this wave stores
    asm volatile("s_waitcnt lgkmcnt(0)\n\ts_barrier" ::: "memory");

    int rm = 0;                         // ring entry consumed at step t
    for (int tp = 0; tp < S_LEN / 2; tp++) {
      const int t0 = 2 * tp, t1 = t0 + 1;
      // -------- even step --------
      if (t0 > 0) readback(t0 - 1);
      serial_step(t0, rm);
      rm = (rm == 5) ? 0 : rm + 1;
      {
        int ts = t0 + 4 + uw;           // finish pending xp tile
        if (ts < S_LEN) { produce(em); em += 2; if (em >= 6) em -= 6; }
        int tn = t0 + 6 + uw;           // issue e loads for next tile
        if (tn < S_LEN) {
          const float* pe = emb + (size_t)xid_pref * DIM + q * 8;
#pragma unroll
          for (int kt = 0; kt < 4; kt++) {
            eld[kt * 2]     = *(const float4*)(pe + kt * 32);
            eld[kt * 2 + 1] = *(const float4*)(pe + kt * 32 + 4);
          }
          if (tn + 2 < S_LEN)
            xid_pref = x[(size_t)(r0u + l15) * S_LEN + tn + 2];
        }
      }
      // chunk c fully in hout after readback(32c+31) which ran this step
      if (flags != nullptr && t0 > 0 && (t0 & 31) == 0)
        asm volatile("s_waitcnt vmcnt(0)" ::: "memory");
      asm volatile("s_waitcnt lgkmcnt(0)\n\ts_barrier" ::: "memory");
      if (flags != nullptr && t0 > 0 && (t0 & 31) == 0 && tid == 0)
        __hip_atomic_store(&flags[blockIdx.x * 8 + (t0 >> 5) - 1], t0 >> 5,
                           __ATOMIC_RELEASE, __HIP_MEMORY_SCOPE_AGENT);
      // -------- odd step --------
      readback(t0);
      serial_step(t1, rm);
      rm = (rm == 5) ? 0 : rm + 1;
      asm volatile("s_waitcnt lgkmcnt(0)\n\ts_barrier" ::: "memory");
    }
    // epilogue: last h slice + chunk 7 publish
    readback(S_LEN - 1);
    if (flags != nullptr) {
      asm volatile("s_waitcnt vmcnt(0)" ::: "memory");
      __syncthreads();
      if (tid == 0)
        __hip_atomic_store(&flags[blockIdx.x * 8 + 7], 8,
                           __ATOMIC_RELEASE, __HIP_MEMORY_SCOPE_AGENT);
    }
  } else {
    // ========================= TAIL ROLE =========================
    const int bt = blockIdx.x - NCORE;   // 0..127, rows bt*8 .. bt*8+7
    const int u  = bt >> 1;              // paired core block / flag unit
    float w2g[5][8], Gs[5], Bs[5], wrow[5];
#pragma unroll
    for (int j = 0; j < 8; j++) {
      int c = l15 * 8 + j;
      float gc = g1[c];
#pragma unroll
      for (int jj = 0; jj < 5; jj++) w2g[jj][j] = Wih2[jj * DIM + c] * gc;
    }
#pragma unroll
    for (int jj = 0; jj < 5; jj++) { Gs[jj] = 0.f; Bs[jj] = 0.f; }
    for (int c = 0; c < DIM; c++) {
      float gc = g1[c], bc = be1[c];
#pragma unroll
      for (int jj = 0; jj < 5; jj++) {
        float w = Wih2[jj * DIM + c];
        Gs[jj] += w * gc; Bs[jj] += w * bc;
      }
    }
    const float validf = (l15 < 5) ? 1.f : 0.f;
    float t2_l = 0.f, g2_l = 0.f, be2_l = 0.f, wrow_z[5];
    (void)wrow_z;
    if (l15 < 5) {
      t2_l = bih2[l15] + bhh2[l15];
      g2_l = g2[l15]; be2_l = be2[l15];
#pragma unroll
      for (int jj = 0; jj < 5; jj++) wrow[jj] = Whh2[l15 * 5 + jj];
    } else {
#pragma unroll
      for (int jj = 0; jj < 5; jj++) wrow[jj] = 0.f;
    }
    float h2rep[5] = {0, 0, 0, 0, 0}, pool_l = 0.f;
    const int rowg = bt * 8 + uw * 4 + q;          // this q-group's row
    const unsigned short* hb = hout + (size_t)rowg * S_LEN * DIM;
    const int idx = (l15 < 5) ? l15 : 0;

    for (int c8 = 0; c8 < 8; c8++) {
      if (tid == 0) {
        while (__hip_atomic_load(&flags[u * 8 + c8], __ATOMIC_RELAXED,
                                 __HIP_MEMORY_SCOPE_AGENT) < c8 + 1)
          __builtin_amdgcn_s_sleep(2);
      }
      __syncthreads();
      __builtin_amdgcn_fence(__ATOMIC_ACQUIRE, "agent");   // reader-side inv
      // phase A: LN1+proj, one t per iter per q-group (4 rows in parallel)
      for (int tt = 0; tt < 32; tt++) {
        uint4 cur = *(const uint4*)(hb + (size_t)(c8 * 32 + tt) * DIM + l15 * 8);
        float hv[8];
        hv[0] = __uint_as_float(cur.x << 16); hv[1] = __uint_as_float(cur.x & 0xffff0000u);
        hv[2] = __uint_as_float(cur.y << 16); hv[3] = __uint_as_float(cur.y & 0xffff0000u);
        hv[4] = __uint_as_float(cur.z << 16); hv[5] = __uint_as_float(cur.z & 0xffff0000u);
        hv[6] = __uint_as_float(cur.w << 16); hv[7] = __uint_as_float(cur.w & 0xffff0000u);
        float s = 0.f, sq = 0.f, d[5] = {0, 0, 0, 0, 0};
#pragma unroll
        for (int j = 0; j < 8; j++) {
          float v = hv[j];
          s += v; sq += v * v;
#pragma unroll
          for (int jj = 0; jj < 5; jj++) d[jj] = fmaf(w2g[jj][j], v, d[jj]);
        }
        red_level7<0x124>(s, sq, d);
        red_level7<0x128>(s, sq, d);
        red_level7<0x39>(s, sq, d);
        red_level7<0x4E>(s, sq, d);
        float mean = s * (1.f / 128.f);
        float var  = sq * (1.f / 128.f) - mean * mean;
        float rstd = rsqrtf(var + EPSL);
        float p[5];
#pragma unroll
        for (int jj = 0; jj < 5; jj++)
          p[jj] = rstd * (d[jj] - mean * Gs[jj]) + Bs[jj];
        float psel = (l15 == 0) ? p[0] : (l15 == 1) ? p[1] :
                     (l15 == 2) ? p[2] : (l15 == 3) ? p[3] : p[4];
        if (l15 < 5) p_lds[uw][q][tt][l15] = psel;
      }
      asm volatile("s_waitcnt lgkmcnt(0)" ::: "memory");   // wave-local
      // phase B: 32 serial RNN2/LN2/pool steps (q-group owns one row)
      for (int s = 0; s < 32; s++) {
        float pv = p_lds[uw][q][s][idx];
        float a = pv + t2_l;
#pragma unroll
        for (int jj = 0; jj < 5; jj++) a = fmaf(wrow[jj], h2rep[jj], a);
        float xn = tanh_fast(a);
        float s2 = dpp_sum16(xn * validf) * 0.2f;
        float dd = xn - s2;
        float v2 = dpp_sum16(dd * dd * validf) * 0.2f;
        float r2 = rsqrtf(v2 + EPSL);
        pool_l += dd * r2 * g2_l + be2_l;
        h2rep[0] = bcast16<0>(xn); h2rep[1] = bcast16<1>(xn);
        h2rep[2] = bcast16<2>(xn); h2rep[3] = bcast16<3>(xn);
        h2rep[4] = bcast16<4>(xn);
      }
    }
    float lg = pool_l * (1.f / 256.f);
    float mx = dpp_max16((l15 < 5) ? lg : -3.0e38f);
    float e  = (l15 < 5) ? __expf(lg - mx) : 0.f;
    float sm = dpp_sum16(e);
    if (l15 < 5) out[(size_t)rowg * 5 + l15] = e / sm;
  }
}

// ============ rnn_tail_r11: fallback tail (ws too small for flags) =========
__global__ __launch_bounds__(256, 2)
void rnn_tail_r11(const unsigned short* __restrict__ hall,
                  const float* __restrict__ g1,  const float* __restrict__ be1,
                  const float* __restrict__ Wih2, const float* __restrict__ bih2,
                  const float* __restrict__ Whh2, const float* __restrict__ bhh2,
                  const float* __restrict__ g2,  const float* __restrict__ be2,
                  float* __restrict__ out)
{
  __shared__ float p_lds[4][4][8];
  const int tid  = threadIdx.x;
  const int wave = tid >> 6;
  const int lane = tid & 63;
  const int l15  = lane & 15;
  const int q    = lane >> 4;
  const int b    = blockIdx.x * 4 + wave;

  float w2g[5][8], Gs[5], Bs[5], wrow[5];
#pragma unroll
  for (int j = 0; j < 8; j++) {
    int c = l15 * 8 + j;
    float gc = g1[c];
#pragma unroll
    for (int jj = 0; jj < 5; jj++) w2g[jj][j] = Wih2[jj * DIM + c] * gc;
  }
#pragma unroll
  for (int jj = 0; jj < 5; jj++) { Gs[jj] = 0.f; Bs[jj] = 0.f; }
  for (int c = 0; c < DIM; c++) {
    float gc = g1[c], bc = be1[c];
#pragma unroll
    for (int jj = 0; jj < 5; jj++) {
      float w = Wih2[jj * DIM + c];
      Gs[jj] += w * gc; Bs[jj] += w * bc;
    }
  }
  const float validf = (l15 < 5) ? 1.f : 0.f;
  float t2_l = 0.f, g2_l = 0.f, be2_l = 0.f;
  if (l15 < 5) {
    t2_l = bih2[l15] + bhh2[l15];
    g2_l = g2[l15]; be2_l = be2[l15];
#pragma unroll
    for (int jj = 0; jj < 5; jj++) wrow[jj] = Whh2[l15 * 5 + jj];
  } else {
#pragma unroll
    for (int jj = 0; jj < 5; jj++) wrow[jj] = 0.f;
  }
  float h2rep[5];
#pragma unroll
  for (int jj = 0; jj < 5; jj++) h2rep[jj] = 0.f;
  float pool_l = 0.f;

  const unsigned short* hb = hall + (size_t)b * S_LEN * DIM;
  uint4 hpre = *(const uint4*)(hb + (size_t)q * DIM + l15 * 8);

  for (int t0 = 0; t0 < S_LEN; t0 += 4) {
    uint4 cur = hpre;
    if (t0 + 4 < S_LEN)
      hpre = *(const uint4*)(hb + (size_t)(t0 + 4 + q) * DIM + l15 * 8);
    float hv[8];
    hv[0] = __uint_as_float(cur.x << 16); hv[1] = __uint_as_float(cur.x & 0xffff0000u);
    hv[2] = __uint_as_float(cur.y << 16); hv[3] = __uint_as_float(cur.y & 0xffff0000u);
    hv[4] = __uint_as_float(cur.z << 16); hv[5] = __uint_as_float(cur.z & 0xffff0000u);
    hv[6] = __uint_as_float(cur.w << 16); hv[7] = __uint_as_float(cur.w & 0xffff0000u);
    float s = 0.f, sq = 0.f, d[5] = {0, 0, 0, 0, 0};
#pragma unroll
    for (int j = 0; j < 8; j++) {
      float v = hv[j];
      s += v; sq += v * v;
#pragma unroll
      for (int jj = 0; jj < 5; jj++) d[jj] = fmaf(w2g[jj][j], v, d[jj]);
    }
    red_level7<0x124>(s, sq, d);
    red_level7<0x128>(s, sq, d);
    red_level7<0x39>(s, sq, d);
    red_level7<0x4E>(s, sq, d);
    float mean = s * (1.f / 128.f);
    float var  = sq * (1.f / 128.f) - mean * mean;
    float rstd = rsqrtf(var + EPSL);
    float p[5];
#pragma unroll
    for (int jj = 0; jj < 5; jj++)
      p[jj] = rstd * (d[jj] - mean * Gs[jj]) + Bs[jj];
    float psel = (l15 == 0) ? p[0] : (l15 == 1) ? p[1] :
                 (l15 == 2) ? p[2] : (l15 == 3) ? p[3] : p[4];
    if (l15 < 5) p_lds[wave][q][l15] = psel;
    asm volatile("s_waitcnt lgkmcnt(0)" ::: "memory");
    const int idx = (l15 < 5) ? l15 : 0;
#pragma unroll
    for (int g = 0; g < 4; g++) {
      float pv = p_lds[wave][g][idx];
      float a = pv + t2_l;
#pragma unroll
      for (int jj = 0; jj < 5; jj++) a = fmaf(wrow[jj], h2rep[jj], a);
      float xn = tanh_fast(a);
      float s2 = dpp_sum16(xn * validf) * 0.2f;
      float dd = xn - s2;
      float v2 = dpp_sum16(dd * dd * validf) * 0.2f;
      float r2 = rsqrtf(v2 + EPSL);
      pool_l += dd * r2 * g2_l + be2_l;
      h2rep[0] = bcast16<0>(xn); h2rep[1] = bcast16<1>(xn);
      h2rep[2] = bcast16<2>(xn); h2rep[3] = bcast16<3>(xn);
      h2rep[4] = bcast16<4>(xn);
    }
  }

  float lg = pool_l * (1.f / 256.f);
  float mx = dpp_max16((l15 < 5) ? lg : -3.0e38f);
  float e  = (l15 < 5) ? __expf(lg - mx) : 0.f;
  float sm = dpp_sum16(e);
  if (q == 0 && l15 < 5) out[(size_t)b * 5 + l15] = e / sm;
}

extern "C" void kernel_launch(void* const* d_in, const int* in_sizes, int n_in,
                              void* d_out, int out_size, void* d_ws, size_t ws_size,
                              hipStream_t stream) {
  (void)in_sizes; (void)n_in; (void)out_size;
  const int*   x    = (const int*)  d_in[0];
  const float* emb  = (const float*)d_in[1];
  const float* Wih1 = (const float*)d_in[2];
  const float* bih1 = (const float*)d_in[3];
  const float* Whh1 = (const float*)d_in[4];
  const float* bhh1 = (const float*)d_in[5];
  const float* g1   = (const float*)d_in[6];
  const float* be1  = (const float*)d_in[7];
  const float* Wih2 = (const float*)d_in[8];
  const float* bih2 = (const float*)d_in[9];
  const float* Whh2 = (const float*)d_in[10];
  const float* bhh2 = (const float*)d_in[11];
  const float* g2   = (const float*)d_in[12];
  const float* be2  = (const float*)d_in[13];
  float* out = (float*)d_out;

  const size_t HBYTES = (size_t)1024 * S_LEN * DIM * 2;   // 64 MiB bf16 h
  unsigned short* hws = (unsigned short*)d_ws;

  if (ws_size >= HBYTES + 4096) {
    int* flags = (int*)((char*)d_ws + HBYTES);
    rnn_fused<<<dim3(NCORE + 128), dim3(128), 0, stream>>>(
        x, emb, Wih1, bih1, Whh1, bhh1, g1, be1,
        Wih2, bih2, Whh2, bhh2, g2, be2, hws, flags, out);
  } else {
    // fallback: core-only (no tail blocks, flags = nullptr) + R11 tail
    rnn_fused<<<dim3(NCORE), dim3(128), 0, stream>>>(
        x, emb, Wih1, bih1, Whh1, bhh1, g1, be1,
        Wih2, bih2, Whh2, bhh2, g2, be2, hws, nullptr, out);
    rnn_tail_r11<<<dim3(256), dim3(256), 0, stream>>>(
        hws, g1, be1, Wih2, bih2, Whh2, bhh2, g2, be2, out);
  }
}

// Round 4
// 299.090 us; speedup vs baseline: 1.3191x; 1.3191x over previous
//
#include <hip/hip_runtime.h>
#include <stdint.h>

#define S_LEN 256
#define DIM   128
#define EPSL  1e-5f

typedef __bf16 bf16x8 __attribute__((ext_vector_type(8)));
typedef float  f32x4  __attribute__((ext_vector_type(4)));

__device__ __forceinline__ unsigned short f2bf_bits(float f) {
  union { float f; unsigned int u; } v; v.f = f;
  unsigned int r = v.u + 0x7fffu + ((v.u >> 16) & 1u);   // RTNE (init paths)
  return (unsigned short)(r >> 16);
}
__device__ __forceinline__ unsigned f2bf_rhu(float f) {
  return (__float_as_uint(f) + 0x8000u) >> 16;
}
__device__ __forceinline__ unsigned pack_rhu(float lo, float hi) {
  return __builtin_amdgcn_perm(__float_as_uint(hi) + 0x8000u,
                               __float_as_uint(lo) + 0x8000u, 0x07060302u);
}
// tanh(x) = 1 - 2/(e^{2x}+1): ~1e-6 rel err, exact at +-inf.
__device__ __forceinline__ float tanh_fast(float x) {
  float e = __expf(2.f * x);
  return 1.f - 2.f * __builtin_amdgcn_rcpf(e + 1.f);
}

template<int CTRL>
__device__ __forceinline__ float dpp_rot_add(float v) {
  int r = __builtin_amdgcn_update_dpp(0, __float_as_int(v), CTRL, 0xF, 0xF, true);
  return v + __int_as_float(r);
}
template<int CTRL>
__device__ __forceinline__ float dpp_rot_max(float v) {
  int r = __builtin_amdgcn_update_dpp(0, __float_as_int(v), CTRL, 0xF, 0xF, true);
  return fmaxf(v, __int_as_float(r));
}
__device__ __forceinline__ float dpp_sum16(float v) {
  v = dpp_rot_add<0x124>(v); v = dpp_rot_add<0x128>(v);
  v = dpp_rot_add<0x39>(v);  v = dpp_rot_add<0x4E>(v);
  return v;
}
__device__ __forceinline__ float dpp_max16(float v) {
  v = dpp_rot_max<0x124>(v); v = dpp_rot_max<0x128>(v);
  v = dpp_rot_max<0x39>(v);  v = dpp_rot_max<0x4E>(v);
  return v;
}
template<int CTRL>
__device__ __forceinline__ void red_level7(float& s, float& sq, float* d) {
  s  = dpp_rot_add<CTRL>(s);
  sq = dpp_rot_add<CTRL>(sq);
#pragma unroll
  for (int j = 0; j < 5; j++) d[j] = dpp_rot_add<CTRL>(d[j]);
}
template<int JJ>
__device__ __forceinline__ float bcast16(float v) {
  int r = __builtin_amdgcn_ds_swizzle(__float_as_int(v), (JJ << 5) | 0x10);
  return __int_as_float(r);
}

union Frag8 { unsigned short us[8]; bf16x8 v; int4 i4; };

// ================= rnn_main4: R0 dataflow re-partitioned onto 4 waves ======
// Core blocks (0..63), 4 waves (1 per SIMD). Each wave owns 32 h-dims
// (2 dim-groups of 16): per step reads the 4 shared A-frags (16 ds_read_b128
// per CU vs R0's 32 — LDS pipe halved), runs two independent 2+2 MFMA chains,
// 8 tanh, h_bf write, hout store, self-produces xpacc[t+1] for its own dims
// (off-chain), and stages its 4 batch rows' e pipeline (ALL waves stage —
// balanced, unlike R0 where waves 4-7 were the barrier stragglers).
// One barrier per step, same flag protocol as R0. Tail blocks (64..191):
// 8 rows each, 4 waves — R0's tail math with wave&7 -> wave&3.
__global__ __launch_bounds__(256, 1)
void rnn_main4(const int* __restrict__ x, const float* __restrict__ emb,
               const float* __restrict__ Wih1, const float* __restrict__ bih1,
               const float* __restrict__ Whh1, const float* __restrict__ bhh1,
               const float* __restrict__ g1, const float* __restrict__ be1,
               const float* __restrict__ Wih2, const float* __restrict__ bih2,
               const float* __restrict__ Whh2, const float* __restrict__ bhh2,
               const float* __restrict__ g2, const float* __restrict__ be2,
               unsigned short* __restrict__ hout, int* flags,
               float* __restrict__ out)
{
  __shared__ __align__(16) unsigned short h_bf[2][16 * 128];   // 8 KB
  __shared__ __align__(16) unsigned short e_bf[2][16 * 128];   // 8 KB
  __shared__ int x_tile[16 * 256];                             // 16 KB
  __shared__ __align__(16) float p_lds[4][2][32][8];           // 8 KB (tail)

  const int tid  = threadIdx.x;
  const int wave = tid >> 6;
  const int lane = tid & 63;
  const int l15  = lane & 15;
  const int q    = lane >> 4;

  if (blockIdx.x < 64) {
    // ========================= CORE ROLE =========================
    const int r0 = blockIdx.x * 16;
    for (int i = tid; i < 16 * 256; i += 256)
      x_tile[i] = x[(size_t)(r0 + (i >> 8)) * S_LEN + (i & 255)];
    for (int i = tid; i < 16 * 128; i += 256) h_bf[1][i] = 0;  // h_{-1} = 0

    // --- per-wave dims: group g in {0,1}: d = wave*32 + g*16 + l15 ---
    float bias1v[2];
    bf16x8 wh[2][4], wihv[2][4];
#pragma unroll
    for (int g = 0; g < 2; g++) {
      const int d = wave * 32 + g * 16 + l15;
      bias1v[g] = bih1[d] + bhh1[d];
#pragma unroll
      for (int kt = 0; kt < 4; kt++) {
        int k0 = kt * 32 + q * 8;
        Frag8 fh, fa;
#pragma unroll
        for (int j = 0; j < 8; j++) {
          fh.us[j] = f2bf_bits(Whh1[d * DIM + k0 + j]);
          fa.us[j] = f2bf_bits(Wih1[d * DIM + k0 + j]);
        }
        wh[g][kt] = fh.v; wihv[g][kt] = fa.v;
      }
    }

    const int gm   = wave * 4 + q;       // staging row (all 4 waves)
    const int goct = l15;
    const int gdst = gm * 128 + ((goct ^ gm) & 15) * 8;
    float pf[2][8];
    __syncthreads();                     // x_tile, h_bf[1] ready

    {                                    // stage e[0],e[1]; preload e[2],e[3]
      float ta[8], tb[8];
      { int xid = x_tile[gm * 256 + 0];
        const float* pe = emb + (size_t)xid * DIM + goct * 8;
#pragma unroll
        for (int j = 0; j < 8; j++) ta[j] = pe[j]; }
      { int xid = x_tile[gm * 256 + 1];
        const float* pe = emb + (size_t)xid * DIM + goct * 8;
#pragma unroll
        for (int j = 0; j < 8; j++) tb[j] = pe[j]; }
      { int xid = x_tile[gm * 256 + 2];
        const float* pe = emb + (size_t)xid * DIM + goct * 8;
#pragma unroll
        for (int j = 0; j < 8; j++) pf[0][j] = pe[j]; }
      { int xid = x_tile[gm * 256 + 3];
        const float* pe = emb + (size_t)xid * DIM + goct * 8;
#pragma unroll
        for (int j = 0; j < 8; j++) pf[1][j] = pe[j]; }
      Frag8 pa, pb;
#pragma unroll
      for (int j = 0; j < 8; j++) { pa.us[j] = f2bf_bits(ta[j]); pb.us[j] = f2bf_bits(tb[j]); }
      *(int4*)&e_bf[0][gdst] = pa.i4;
      *(int4*)&e_bf[1][gdst] = pb.i4;
    }
    __syncthreads();                     // e_bf[0..1] ready

    // xpacc[0] for both groups (two 2+2 chains, R2-validated numerics)
    f32x4 xpacc[2];
    {
      int sw0 = ((q ^ l15) & 15) * 8;
      int sw1 = (((4 + q) ^ l15) & 15) * 8;
      int sw2 = (((8 + q) ^ l15) & 15) * 8;
      int sw3 = (((12 + q) ^ l15) & 15) * 8;
      bf16x8 e0 = *(const bf16x8*)&e_bf[0][l15 * 128 + sw0];
      bf16x8 e1 = *(const bf16x8*)&e_bf[0][l15 * 128 + sw1];
      bf16x8 e2 = *(const bf16x8*)&e_bf[0][l15 * 128 + sw2];
      bf16x8 e3 = *(const bf16x8*)&e_bf[0][l15 * 128 + sw3];
#pragma unroll
      for (int g = 0; g < 2; g++) {
        f32x4 a = {bias1v[g], bias1v[g], bias1v[g], bias1v[g]};
        f32x4 b = {0.f, 0.f, 0.f, 0.f};
        a = __builtin_amdgcn_mfma_f32_16x16x32_bf16(e0, wihv[g][0], a, 0, 0, 0);
        b = __builtin_amdgcn_mfma_f32_16x16x32_bf16(e2, wihv[g][2], b, 0, 0, 0);
        a = __builtin_amdgcn_mfma_f32_16x16x32_bf16(e1, wihv[g][1], a, 0, 0, 0);
        b = __builtin_amdgcn_mfma_f32_16x16x32_bf16(e3, wihv[g][3], b, 0, 0, 0);
        xpacc[g] = a + b;
      }
    }
    asm volatile("s_waitcnt lgkmcnt(0)\n\ts_barrier" ::: "memory");

#pragma unroll 2
    for (int t = 0; t < S_LEN; t++) {
      const int rb = (t + 1) & 1;        // h_{t-1}
      const int wb = t & 1;
      unsigned short usv[2][4];
      {
        // ---- serial chain: shared A-frags, two independent 2+2 chains ----
        int sw0 = ((q ^ l15) & 15) * 8;
        int sw1 = (((4 + q) ^ l15) & 15) * 8;
        int sw2 = (((8 + q) ^ l15) & 15) * 8;
        int sw3 = (((12 + q) ^ l15) & 15) * 8;
        bf16x8 a0 = *(const bf16x8*)&h_bf[rb][l15 * 128 + sw0];
        bf16x8 a1 = *(const bf16x8*)&h_bf[rb][l15 * 128 + sw1];
        bf16x8 a2 = *(const bf16x8*)&h_bf[rb][l15 * 128 + sw2];
        bf16x8 a3 = *(const bf16x8*)&h_bf[rb][l15 * 128 + sw3];
#pragma unroll
        for (int g = 0; g < 2; g++) {
          f32x4 acc  = xpacc[g];
          f32x4 accb = {0.f, 0.f, 0.f, 0.f};
          acc  = __builtin_amdgcn_mfma_f32_16x16x32_bf16(a0, wh[g][0], acc,  0, 0, 0);
          accb = __builtin_amdgcn_mfma_f32_16x16x32_bf16(a2, wh[g][2], accb, 0, 0, 0);
          acc  = __builtin_amdgcn_mfma_f32_16x16x32_bf16(a1, wh[g][1], acc,  0, 0, 0);
          accb = __builtin_amdgcn_mfma_f32_16x16x32_bf16(a3, wh[g][3], accb, 0, 0, 0);
          acc += accb;
          const int c = wave * 32 + g * 16 + l15;
          const int oct = c >> 3;
#pragma unroll
          for (int r = 0; r < 4; r++) {  // D-layout: row = q*4 + r, col = c
            int row = q * 4 + r;
            unsigned short us = (unsigned short)f2bf_rhu(tanh_fast(acc[r]));
            usv[g][r] = us;
            h_bf[wb][row * 128 + ((oct ^ row) & 15) * 8 + (c & 7)] = us;
          }
        }
      }
#pragma unroll
      for (int g = 0; g < 2; g++) {      // off-chain global stores
        const int c = wave * 32 + g * 16 + l15;
#pragma unroll
        for (int r = 0; r < 4; r++) {
          int row = q * 4 + r;
          hout[((size_t)(r0 + row) * S_LEN + t) * DIM + c] = usv[g][r];
        }
      }

      if (t + 1 < S_LEN) {               // xpacc[t+1] (off-chain)
        int sw0 = ((q ^ l15) & 15) * 8;
        int sw1 = (((4 + q) ^ l15) & 15) * 8;
        int sw2 = (((8 + q) ^ l15) & 15) * 8;
        int sw3 = (((12 + q) ^ l15) & 15) * 8;
        const unsigned short* eb = &e_bf[(t + 1) & 1][l15 * 128];
        bf16x8 e0 = *(const bf16x8*)&eb[sw0];
        bf16x8 e1 = *(const bf16x8*)&eb[sw1];
        bf16x8 e2 = *(const bf16x8*)&eb[sw2];
        bf16x8 e3 = *(const bf16x8*)&eb[sw3];
#pragma unroll
        for (int g = 0; g < 2; g++) {
          f32x4 a = {bias1v[g], bias1v[g], bias1v[g], bias1v[g]};
          f32x4 b = {0.f, 0.f, 0.f, 0.f};
          a = __builtin_amdgcn_mfma_f32_16x16x32_bf16(e0, wihv[g][0], a, 0, 0, 0);
          b = __builtin_amdgcn_mfma_f32_16x16x32_bf16(e2, wihv[g][2], b, 0, 0, 0);
          a = __builtin_amdgcn_mfma_f32_16x16x32_bf16(e1, wihv[g][1], a, 0, 0, 0);
          b = __builtin_amdgcn_mfma_f32_16x16x32_bf16(e3, wihv[g][3], b, 0, 0, 0);
          xpacc[g] = a + b;
        }
      }

      {                                  // staging pipeline (all waves)
        if (t + 2 < S_LEN) {             // stage e[t+2] (gathered at t-2)
          int4 pk;
          pk.x = pack_rhu(pf[t & 1][0], pf[t & 1][1]);
          pk.y = pack_rhu(pf[t & 1][2], pf[t & 1][3]);
          pk.z = pack_rhu(pf[t & 1][4], pf[t & 1][5]);
          pk.w = pack_rhu(pf[t & 1][6], pf[t & 1][7]);
          *(int4*)&e_bf[t & 1][gdst] = pk;
        }
        if (t + 4 < S_LEN) {             // issue gather e[t+4] (2-step cover)
          int xid = x_tile[gm * 256 + t + 4];
          const float* pe = emb + (size_t)xid * DIM + goct * 8;
#pragma unroll
          for (int j = 0; j < 8; j++) pf[t & 1][j] = pe[j];
        }
      }
      // chunk boundary: drain h stores so the post-barrier flag publish
      // covers the whole block's chunk.
      if (flags != nullptr && (t & 31) == 31)
        asm volatile("s_waitcnt vmcnt(0)" ::: "memory");
      asm volatile("s_waitcnt lgkmcnt(0)\n\ts_barrier" ::: "memory");
      if (flags != nullptr && (t & 31) == 31 && tid == 0)
        __hip_atomic_store(&flags[blockIdx.x * 8 + (t >> 5)], (t >> 5) + 1,
                           __ATOMIC_RELEASE, __HIP_MEMORY_SCOPE_AGENT);
    }
  } else {
    // ========================= TAIL ROLE =========================
    const int bt = blockIdx.x - 64;      // 0..127, rows bt*8 .. bt*8+7
    const int u  = bt >> 1;              // paired core block / flag unit
    float w2g[5][8], Gs[5], Bs[5], wrow[5];
#pragma unroll
    for (int j = 0; j < 8; j++) {
      int c = l15 * 8 + j;               // plain row-major channels
      float gc = g1[c];
#pragma unroll
      for (int jj = 0; jj < 5; jj++) w2g[jj][j] = Wih2[jj * DIM + c] * gc;
    }
#pragma unroll
    for (int jj = 0; jj < 5; jj++) { Gs[jj] = 0.f; Bs[jj] = 0.f; }
    for (int c = 0; c < DIM; c++) {
      float gc = g1[c], bc = be1[c];
#pragma unroll
      for (int jj = 0; jj < 5; jj++) {
        float w = Wih2[jj * DIM + c];
        Gs[jj] += w * gc; Bs[jj] += w * bc;
      }
    }
    const float validf = (l15 < 5) ? 1.f : 0.f;
    float t2_l = 0.f, g2_l = 0.f, be2_l = 0.f, wrow_[5];
    (void)wrow_;
    if (l15 < 5) {
      t2_l = bih2[l15] + bhh2[l15];
      g2_l = g2[l15]; be2_l = be2[l15];
#pragma unroll
      for (int jj = 0; jj < 5; jj++) wrow[jj] = Whh2[l15 * 5 + jj];
    } else {
#pragma unroll
      for (int jj = 0; jj < 5; jj++) wrow[jj] = 0.f;
    }
    float h2rep[5] = {0, 0, 0, 0, 0}, pool_l = 0.f;
    const int rowg = bt * 8 + wave * 2 + (q & 1);   // this group's row
    const unsigned short* hb = hout + (size_t)rowg * S_LEN * DIM;
    const int idx = (l15 < 5) ? l15 : 0;

    for (int c8 = 0; c8 < 8; c8++) {
      if (tid == 0) {                    // poisoned flag is negative: waits
        while (__hip_atomic_load(&flags[u * 8 + c8], __ATOMIC_RELAXED,
                                 __HIP_MEMORY_SCOPE_AGENT) < c8 + 1)
          __builtin_amdgcn_s_sleep(2);
      }
      __syncthreads();
      __builtin_amdgcn_fence(__ATOMIC_ACQUIRE, "agent");   // reader-side inv
      // phase A: LN1+proj for this chunk (2 rows x 32 t over 2 sub-groups)
      for (int tt = 0; tt < 16; tt++) {
        int toff = tt * 2 + (q >> 1);
        uint4 cur = *(const uint4*)(hb + (size_t)(c8 * 32 + toff) * DIM + l15 * 8);
        float hv[8];
        hv[0] = __uint_as_float(cur.x << 16); hv[1] = __uint_as_float(cur.x & 0xffff0000u);
        hv[2] = __uint_as_float(cur.y << 16); hv[3] = __uint_as_float(cur.y & 0xffff0000u);
        hv[4] = __uint_as_float(cur.z << 16); hv[5] = __uint_as_float(cur.z & 0xffff0000u);
        hv[6] = __uint_as_float(cur.w << 16); hv[7] = __uint_as_float(cur.w & 0xffff0000u);
        float s = 0.f, sq = 0.f, d[5] = {0, 0, 0, 0, 0};
#pragma unroll
        for (int j = 0; j < 8; j++) {
          float v = hv[j];
          s += v; sq += v * v;
#pragma unroll
          for (int jj = 0; jj < 5; jj++) d[jj] = fmaf(w2g[jj][j], v, d[jj]);
        }
        red_level7<0x124>(s, sq, d);
        red_level7<0x128>(s, sq, d);
        red_level7<0x39>(s, sq, d);
        red_level7<0x4E>(s, sq, d);
        float mean = s * (1.f / 128.f);
        float var  = sq * (1.f / 128.f) - mean * mean;
        float rstd = rsqrtf(var + EPSL);
        float p[5];
#pragma unroll
        for (int jj = 0; jj < 5; jj++)
          p[jj] = rstd * (d[jj] - mean * Gs[jj]) + Bs[jj];
        float psel = (l15 == 0) ? p[0] : (l15 == 1) ? p[1] :
                     (l15 == 2) ? p[2] : (l15 == 3) ? p[3] : p[4];
        if (l15 < 5) p_lds[wave][q & 1][toff][l15] = psel;
      }
      asm volatile("s_waitcnt lgkmcnt(0)" ::: "memory");   // wave-local
      // phase B: 32 serial RNN2/LN2/pool steps (group-local, 1 tanh/step)
      for (int s = 0; s < 32; s++) {
        float pv = p_lds[wave][q & 1][s][idx];
        float a = pv + t2_l;
#pragma unroll
        for (int jj = 0; jj < 5; jj++) a = fmaf(wrow[jj], h2rep[jj], a);
        float xn = tanh_fast(a);
        float s2 = dpp_sum16(xn * validf) * 0.2f;
        float dd = xn - s2;
        float v2 = dpp_sum16(dd * dd * validf) * 0.2f;
        float r2 = rsqrtf(v2 + EPSL);
        pool_l += dd * r2 * g2_l + be2_l;
        h2rep[0] = bcast16<0>(xn); h2rep[1] = bcast16<1>(xn);
        h2rep[2] = bcast16<2>(xn); h2rep[3] = bcast16<3>(xn);
        h2rep[4] = bcast16<4>(xn);
      }
    }
    float lg = pool_l * (1.f / 256.f);
    float mx = dpp_max16((l15 < 5) ? lg : -3.0e38f);
    float e  = (l15 < 5) ? __expf(lg - mx) : 0.f;
    float sm = dpp_sum16(e);
    if (q < 2 && l15 < 5)
      out[(size_t)rowg * 5 + l15] = e / sm;
  }
}

// ============ rnn_tail_r11: fallback tail (ws too small for flags) =========
__global__ __launch_bounds__(256, 2)
void rnn_tail_r11(const unsigned short* __restrict__ hall,
                  const float* __restrict__ g1,  const float* __restrict__ be1,
                  const float* __restrict__ Wih2, const float* __restrict__ bih2,
                  const float* __restrict__ Whh2, const float* __restrict__ bhh2,
                  const float* __restrict__ g2,  const float* __restrict__ be2,
                  float* __restrict__ out)
{
  __shared__ float p_lds[4][4][8];
  const int tid  = threadIdx.x;
  const int wave = tid >> 6;
  const int lane = tid & 63;
  const int l15  = lane & 15;
  const int q    = lane >> 4;
  const int b    = blockIdx.x * 4 + wave;

  float w2g[5][8], Gs[5], Bs[5], wrow[5];
#pragma unroll
  for (int j = 0; j < 8; j++) {
    int c = l15 * 8 + j;
    float gc = g1[c];
#pragma unroll
    for (int jj = 0; jj < 5; jj++) w2g[jj][j] = Wih2[jj * DIM + c] * gc;
  }
#pragma unroll
  for (int jj = 0; jj < 5; jj++) { Gs[jj] = 0.f; Bs[jj] = 0.f; }
  for (int c = 0; c < DIM; c++) {
    float gc = g1[c], bc = be1[c];
#pragma unroll
    for (int jj = 0; jj < 5; jj++) {
      float w = Wih2[jj * DIM + c];
      Gs[jj] += w * gc; Bs[jj] += w * bc;
    }
  }
  const float validf = (l15 < 5) ? 1.f : 0.f;
  float t2_l = 0.f, g2_l = 0.f, be2_l = 0.f;
  if (l15 < 5) {
    t2_l = bih2[l15] + bhh2[l15];
    g2_l = g2[l15]; be2_l = be2[l15];
#pragma unroll
    for (int jj = 0; jj < 5; jj++) wrow[jj] = Whh2[l15 * 5 + jj];
  } else {
#pragma unroll
    for (int jj = 0; jj < 5; jj++) wrow[jj] = 0.f;
  }
  float h2rep[5];
#pragma unroll
  for (int jj = 0; jj < 5; jj++) h2rep[jj] = 0.f;
  float pool_l = 0.f;

  const unsigned short* hb = hall + (size_t)b * S_LEN * DIM;
  uint4 hpre = *(const uint4*)(hb + (size_t)q * DIM + l15 * 8);

  for (int t0 = 0; t0 < S_LEN; t0 += 4) {
    uint4 cur = hpre;
    if (t0 + 4 < S_LEN)
      hpre = *(const uint4*)(hb + (size_t)(t0 + 4 + q) * DIM + l15 * 8);
    float hv[8];
    hv[0] = __uint_as_float(cur.x << 16); hv[1] = __uint_as_float(cur.x & 0xffff0000u);
    hv[2] = __uint_as_float(cur.y << 16); hv[3] = __uint_as_float(cur.y & 0xffff0000u);
    hv[4] = __uint_as_float(cur.z << 16); hv[5] = __uint_as_float(cur.z & 0xffff0000u);
    hv[6] = __uint_as_float(cur.w << 16); hv[7] = __uint_as_float(cur.w & 0xffff0000u);
    float s = 0.f, sq = 0.f, d[5] = {0, 0, 0, 0, 0};
#pragma unroll
    for (int j = 0; j < 8; j++) {
      float v = hv[j];
      s += v; sq += v * v;
#pragma unroll
      for (int jj = 0; jj < 5; jj++) d[jj] = fmaf(w2g[jj][j], v, d[jj]);
    }
    red_level7<0x124>(s, sq, d);
    red_level7<0x128>(s, sq, d);
    red_level7<0x39>(s, sq, d);
    red_level7<0x4E>(s, sq, d);
    float mean = s * (1.f / 128.f);
    float var  = sq * (1.f / 128.f) - mean * mean;
    float rstd = rsqrtf(var + EPSL);
    float p[5];
#pragma unroll
    for (int jj = 0; jj < 5; jj++)
      p[jj] = rstd * (d[jj] - mean * Gs[jj]) + Bs[jj];
    float psel = (l15 == 0) ? p[0] : (l15 == 1) ? p[1] :
                 (l15 == 2) ? p[2] : (l15 == 3) ? p[3] : p[4];
    if (l15 < 5) p_lds[wave][q][l15] = psel;
    asm volatile("s_waitcnt lgkmcnt(0)" ::: "memory");
    const int idx = (l15 < 5) ? l15 : 0;
#pragma unroll
    for (int g = 0; g < 4; g++) {
      float pv = p_lds[wave][g][idx];
      float a = pv + t2_l;
#pragma unroll
      for (int jj = 0; jj < 5; jj++) a = fmaf(wrow[jj], h2rep[jj], a);
      float xn = tanh_fast(a);
      float s2 = dpp_sum16(xn * validf) * 0.2f;
      float dd = xn - s2;
      float v2 = dpp_sum16(dd * dd * validf) * 0.2f;
      float r2 = rsqrtf(v2 + EPSL);
      pool_l += dd * r2 * g2_l + be2_l;
      h2rep[0] = bcast16<0>(xn); h2rep[1] = bcast16<1>(xn);
      h2rep[2] = bcast16<2>(xn); h2rep[3] = bcast16<3>(xn);
      h2rep[4] = bcast16<4>(xn);
    }
  }

  float lg = pool_l * (1.f / 256.f);
  float mx = dpp_max16((l15 < 5) ? lg : -3.0e38f);
  float e  = (l15 < 5) ? __expf(lg - mx) : 0.f;
  float sm = dpp_sum16(e);
  if (q == 0 && l15 < 5) out[(size_t)b * 5 + l15] = e / sm;
}

extern "C" void kernel_launch(void* const* d_in, const int* in_sizes, int n_in,
                              void* d_out, int out_size, void* d_ws, size_t ws_size,
                              hipStream_t stream) {
  (void)in_sizes; (void)n_in; (void)out_size;
  const int*   x    = (const int*)  d_in[0];
  const float* emb  = (const float*)d_in[1];
  const float* Wih1 = (const float*)d_in[2];
  const float* bih1 = (const float*)d_in[3];
  const float* Whh1 = (const float*)d_in[4];
  const float* bhh1 = (const float*)d_in[5];
  const float* g1   = (const float*)d_in[6];
  const float* be1  = (const float*)d_in[7];
  const float* Wih2 = (const float*)d_in[8];
  const float* bih2 = (const float*)d_in[9];
  const float* Whh2 = (const float*)d_in[10];
  const float* bhh2 = (const float*)d_in[11];
  const float* g2   = (const float*)d_in[12];
  const float* be2  = (const float*)d_in[13];
  float* out = (float*)d_out;

  const size_t HBYTES = (size_t)1024 * S_LEN * DIM * 2;   // 64 MiB bf16 h
  unsigned short* hws = (unsigned short*)d_ws;

  if (ws_size >= HBYTES + 4096) {
    int* flags = (int*)((char*)d_ws + HBYTES);
    rnn_main4<<<dim3(192), dim3(256), 0, stream>>>(
        x, emb, Wih1, bih1, Whh1, bhh1, g1, be1,
        Wih2, bih2, Whh2, bhh2, g2, be2, hws, flags, out);
  } else {
    // fallback: core-only (no tail blocks, flags = nullptr) + R11 tail
    rnn_main4<<<dim3(64), dim3(256), 0, stream>>>(
        x, emb, Wih1, bih1, Whh1, bhh1, g1, be1,
        Wih2, bih2, Whh2, bhh2, g2, be2, hws, nullptr, out);
    rnn_tail_r11<<<dim3(256), dim3(256), 0, stream>>>(
        hws, g1, be1, Wih2, bih2, Whh2, bhh2, g2, be2, out);
  }
}

// Round 5
// 256.673 us; speedup vs baseline: 1.5370x; 1.1653x over previous
//
#include <hip/hip_runtime.h>
#include <stdint.h>

#define S_LEN 256
#define DIM   128
#define EPSL  1e-5f

typedef __bf16 bf16x8 __attribute__((ext_vector_type(8)));
typedef float  f32x4  __attribute__((ext_vector_type(4)));

__device__ __forceinline__ unsigned short f2bf_bits(float f) {
  union { float f; unsigned int u; } v; v.f = f;
  unsigned int r = v.u + 0x7fffu + ((v.u >> 16) & 1u);   // RTNE (init paths)
  return (unsigned short)(r >> 16);
}
__device__ __forceinline__ unsigned f2bf_rhu(float f) {
  return (__float_as_uint(f) + 0x8000u) >> 16;
}
__device__ __forceinline__ unsigned pack_rhu(float lo, float hi) {
  return __builtin_amdgcn_perm(__float_as_uint(hi) + 0x8000u,
                               __float_as_uint(lo) + 0x8000u, 0x07060302u);
}
// tanh(x) = 1 - 2/(e^{2x}+1): ~1e-6 rel err, exact at +-inf.
__device__ __forceinline__ float tanh_fast(float x) {
  float e = __expf(2.f * x);
  return 1.f - 2.f * __builtin_amdgcn_rcpf(e + 1.f);
}

template<int CTRL>
__device__ __forceinline__ float dpp_rot_add(float v) {
  int r = __builtin_amdgcn_update_dpp(0, __float_as_int(v), CTRL, 0xF, 0xF, true);
  return v + __int_as_float(r);
}
template<int CTRL>
__device__ __forceinline__ float dpp_rot_max(float v) {
  int r = __builtin_amdgcn_update_dpp(0, __float_as_int(v), CTRL, 0xF, 0xF, true);
  return fmaxf(v, __int_as_float(r));
}
__device__ __forceinline__ float dpp_sum16(float v) {
  v = dpp_rot_add<0x124>(v); v = dpp_rot_add<0x128>(v);
  v = dpp_rot_add<0x39>(v);  v = dpp_rot_add<0x4E>(v);
  return v;
}
__device__ __forceinline__ float dpp_max16(float v) {
  v = dpp_rot_max<0x124>(v); v = dpp_rot_max<0x128>(v);
  v = dpp_rot_max<0x39>(v);  v = dpp_rot_max<0x4E>(v);
  return v;
}
template<int CTRL>
__device__ __forceinline__ void red_level7(float& s, float& sq, float* d) {
  s  = dpp_rot_add<CTRL>(s);
  sq = dpp_rot_add<CTRL>(sq);
#pragma unroll
  for (int j = 0; j < 5; j++) d[j] = dpp_rot_add<CTRL>(d[j]);
}
template<int JJ>
__device__ __forceinline__ float bcast16(float v) {
  int r = __builtin_amdgcn_ds_swizzle(__float_as_int(v), (JJ << 5) | 0x10);
  return __int_as_float(r);
}

union Frag8 { unsigned short us[8]; bf16x8 v; int4 i4; };

// ================= rnn_main: R0 structure + BALANCED staging ================
// Core blocks (0-63), 8 waves (2/SIMD — measured optimum across the R0-R4
// structural sweep). Identical to the 177 µs R0 kernel except the e-staging
// pipeline is spread across ALL 8 waves instead of riding on waves 4-7:
// each wave stages 2 batch rows x half-octet granularity (one float4 gather,
// 2 packs, one ds_write_b64 per step ~8 instrs) instead of waves 4-7 doing
// 8-float gathers + b128 writes (~30 instrs) while waves 0-3 idle through
// the barrier. Removes the straggler asymmetry the per-step barrier pays.
// Everything else (serial chain, xpacc, swizzles, flag protocol, tail) is
// byte-identical to R0.
__global__ __launch_bounds__(512, 2)
void rnn_main(const int* __restrict__ x, const float* __restrict__ emb,
              const float* __restrict__ Wih1, const float* __restrict__ bih1,
              const float* __restrict__ Whh1, const float* __restrict__ bhh1,
              const float* __restrict__ g1, const float* __restrict__ be1,
              const float* __restrict__ Wih2, const float* __restrict__ bih2,
              const float* __restrict__ Whh2, const float* __restrict__ bhh2,
              const float* __restrict__ g2, const float* __restrict__ be2,
              unsigned short* __restrict__ hout, int* flags,
              float* __restrict__ out)
{
  __shared__ __align__(16) unsigned short h_bf[2][16 * 128];   // 8 KB
  __shared__ __align__(16) unsigned short e_bf[2][16 * 128];   // 8 KB
  __shared__ int x_tile[16 * 256];                             // 16 KB
  __shared__ __align__(16) float p_lds[8][2][32][8];           // 16 KB (tail)

  const int tid  = threadIdx.x;
  const int wave = tid >> 6;
  const int lane = tid & 63;
  const int l15  = lane & 15;
  const int q    = lane >> 4;

  if (blockIdx.x < 64) {
    // ========================= CORE ROLE =========================
    const int r0 = blockIdx.x * 16;
    for (int i = tid; i < 16 * 256; i += 512)
      x_tile[i] = x[(size_t)(r0 + (i >> 8)) * S_LEN + (i & 255)];
    for (int i = tid; i < 16 * 128; i += 512) h_bf[1][i] = 0;  // h_{-1} = 0

    const int n1 = wave * 16 + l15;
    const float bias1v = bih1[n1] + bhh1[n1];
    bf16x8 wh[4], wih[4];
#pragma unroll
    for (int kt = 0; kt < 4; kt++) {
      int k0 = kt * 32 + q * 8;
      Frag8 fh, fa;
#pragma unroll
      for (int j = 0; j < 8; j++) {
        fh.us[j] = f2bf_bits(Whh1[n1 * DIM + k0 + j]);
        fa.us[j] = f2bf_bits(Wih1[n1 * DIM + k0 + j]);
      }
      wh[kt] = fh.v; wih[kt] = fa.v;
    }

    // ---- balanced staging geometry: every wave stages 2 rows, float4/lane
    const int srow = wave * 2 + (lane >> 5);     // batch row (0..15)
    const int soct = (lane >> 1) & 15;           // octet within the row
    const int ssub = lane & 1;                   // which half of the octet
    const int sdst = srow * 128 + ((soct ^ srow) & 15) * 8 + ssub * 4;
    float4 pf[2];
    __syncthreads();

    {                                  // stage e[0],e[1]; preload e[2],e[3]
      float4 ta, tb;
      { int xid = x_tile[srow * 256 + 0];
        ta = *(const float4*)(emb + (size_t)xid * DIM + soct * 8 + ssub * 4); }
      { int xid = x_tile[srow * 256 + 1];
        tb = *(const float4*)(emb + (size_t)xid * DIM + soct * 8 + ssub * 4); }
      { int xid = x_tile[srow * 256 + 2];
        pf[0] = *(const float4*)(emb + (size_t)xid * DIM + soct * 8 + ssub * 4); }
      { int xid = x_tile[srow * 256 + 3];
        pf[1] = *(const float4*)(emb + (size_t)xid * DIM + soct * 8 + ssub * 4); }
      int2 pa, pb;
      pa.x = (int)pack_rhu(ta.x, ta.y); pa.y = (int)pack_rhu(ta.z, ta.w);
      pb.x = (int)pack_rhu(tb.x, tb.y); pb.y = (int)pack_rhu(tb.z, tb.w);
      *(int2*)&e_bf[0][sdst] = pa;
      *(int2*)&e_bf[1][sdst] = pb;
    }
    __syncthreads();

    f32x4 xpacc = {bias1v, bias1v, bias1v, bias1v};
#pragma unroll
    for (int kt = 0; kt < 4; kt++) {
      int sw = (((kt * 4 + q) ^ l15) & 15) * 8;
      bf16x8 ae = *(const bf16x8*)&e_bf[0][l15 * 128 + sw];
      xpacc = __builtin_amdgcn_mfma_f32_16x16x32_bf16(ae, wih[kt], xpacc, 0, 0, 0);
    }
    asm volatile("s_waitcnt lgkmcnt(0)\n\ts_barrier" ::: "memory");

#pragma unroll 2
    for (int t = 0; t < S_LEN; t++) {
      // ---- serial core: acc seeded with xpacc, ONE depth-4 chain ----
      f32x4 acc = xpacc;
      {
        const int rb = (t + 1) & 1;      // h_{t-1}
#pragma unroll
        for (int kt = 0; kt < 4; kt++) {
          int sw = (((kt * 4 + q) ^ l15) & 15) * 8;
          bf16x8 ahf = *(const bf16x8*)&h_bf[rb][l15 * 128 + sw];
          acc = __builtin_amdgcn_mfma_f32_16x16x32_bf16(ahf, wh[kt], acc, 0, 0, 0);
        }
        const int wb = t & 1;
        const int oct = n1 >> 3;
#pragma unroll
        for (int r = 0; r < 4; r++) {    // D-layout: row = q*4 + r, col = l15
          int row = q * 4 + r;
          unsigned short us = (unsigned short)f2bf_rhu(tanh_fast(acc[r]));
          h_bf[wb][row * 128 + ((oct ^ row) & 15) * 8 + (n1 & 7)] = us;
          hout[((size_t)(r0 + row) * S_LEN + t) * DIM + n1] = us;  // off-chain
        }
      }

      if (t + 1 < S_LEN) {               // e_{t+1}@Wih into regs (off-chain)
        f32x4 a = {bias1v, bias1v, bias1v, bias1v};
#pragma unroll
        for (int kt = 0; kt < 4; kt++) {
          int sw = (((kt * 4 + q) ^ l15) & 15) * 8;
          bf16x8 ae = *(const bf16x8*)&e_bf[(t + 1) & 1][l15 * 128 + sw];
          a = __builtin_amdgcn_mfma_f32_16x16x32_bf16(ae, wih[kt], a, 0, 0, 0);
        }
        xpacc = a;
      }

      {                                  // balanced staging (all 8 waves)
        if (t + 2 < S_LEN) {             // stage e[t+2] (gathered at t-2)
          int2 pk;
          pk.x = (int)pack_rhu(pf[t & 1].x, pf[t & 1].y);
          pk.y = (int)pack_rhu(pf[t & 1].z, pf[t & 1].w);
          *(int2*)&e_bf[t & 1][sdst] = pk;
        }
        if (t + 4 < S_LEN) {             // issue gather e[t+4] (2-step cover)
          int xid = x_tile[srow * 256 + t + 4];
          pf[t & 1] = *(const float4*)(emb + (size_t)xid * DIM + soct * 8 + ssub * 4);
        }
      }
      // chunk boundary: drain this wave's h stores before the barrier so the
      // post-barrier flag publish covers the whole block's chunk.
      if (flags != nullptr && (t & 31) == 31)
        asm volatile("s_waitcnt vmcnt(0)" ::: "memory");
      asm volatile("s_waitcnt lgkmcnt(0)\n\ts_barrier" ::: "memory");
      if (flags != nullptr && (t & 31) == 31 && tid == 0)
        __hip_atomic_store(&flags[blockIdx.x * 8 + (t >> 5)], (t >> 5) + 1,
                           __ATOMIC_RELEASE, __HIP_MEMORY_SCOPE_AGENT);
    }
  } else {
    // ========================= TAIL ROLE =========================
    const int bt = blockIdx.x - 64;      // paired core block
    float w2g[5][8], Gs[5], Bs[5], wrow[5];
#pragma unroll
    for (int j = 0; j < 8; j++) {
      int c = l15 * 8 + j;               // plain row-major channels
      float gc = g1[c];
#pragma unroll
      for (int jj = 0; jj < 5; jj++) w2g[jj][j] = Wih2[jj * DIM + c] * gc;
    }
#pragma unroll
    for (int jj = 0; jj < 5; jj++) { Gs[jj] = 0.f; Bs[jj] = 0.f; }
    for (int c = 0; c < DIM; c++) {
      float gc = g1[c], bc = be1[c];
#pragma unroll
      for (int jj = 0; jj < 5; jj++) {
        float w = Wih2[jj * DIM + c];
        Gs[jj] += w * gc; Bs[jj] += w * bc;
      }
    }
    const float validf = (l15 < 5) ? 1.f : 0.f;
    float t2_l = 0.f, g2_l = 0.f, be2_l = 0.f;
    if (l15 < 5) {
      t2_l = bih2[l15] + bhh2[l15];
      g2_l = g2[l15]; be2_l = be2[l15];
#pragma unroll
      for (int jj = 0; jj < 5; jj++) wrow[jj] = Whh2[l15 * 5 + jj];
    } else {
#pragma unroll
      for (int jj = 0; jj < 5; jj++) wrow[jj] = 0.f;
    }
    float h2rep[5] = {0, 0, 0, 0, 0}, pool_l = 0.f;
    const int row_l = 2 * wave + (q & 1);          // this group's row
    const unsigned short* hb =
        hout + (size_t)(bt * 16 + row_l) * S_LEN * DIM;
    const int idx = (l15 < 5) ? l15 : 0;

    for (int c8 = 0; c8 < 8; c8++) {
      if (tid == 0) {                    // poisoned flag is negative: waits
        while (__hip_atomic_load(&flags[bt * 8 + c8], __ATOMIC_RELAXED,
                                 __HIP_MEMORY_SCOPE_AGENT) < c8 + 1)
          __builtin_amdgcn_s_sleep(2);
      }
      __syncthreads();
      __builtin_amdgcn_fence(__ATOMIC_ACQUIRE, "agent");   // reader-side inv
      // phase A: LN1+proj for this chunk (2 rows x 32 t over 4 groups)
      for (int tt = 0; tt < 16; tt++) {
        int toff = tt * 2 + (q >> 1);
        uint4 cur = *(const uint4*)(hb + (size_t)(c8 * 32 + toff) * DIM + l15 * 8);
        float hv[8];
        hv[0] = __uint_as_float(cur.x << 16); hv[1] = __uint_as_float(cur.x & 0xffff0000u);
        hv[2] = __uint_as_float(cur.y << 16); hv[3] = __uint_as_float(cur.y & 0xffff0000u);
        hv[4] = __uint_as_float(cur.z << 16); hv[5] = __uint_as_float(cur.z & 0xffff0000u);
        hv[6] = __uint_as_float(cur.w << 16); hv[7] = __uint_as_float(cur.w & 0xffff0000u);
        float s = 0.f, sq = 0.f, d[5] = {0, 0, 0, 0, 0};
#pragma unroll
        for (int j = 0; j < 8; j++) {
          float v = hv[j];
          s += v; sq += v * v;
#pragma unroll
          for (int jj = 0; jj < 5; jj++) d[jj] = fmaf(w2g[jj][j], v, d[jj]);
        }
        red_level7<0x124>(s, sq, d);
        red_level7<0x128>(s, sq, d);
        red_level7<0x39>(s, sq, d);
        red_level7<0x4E>(s, sq, d);
        float mean = s * (1.f / 128.f);
        float var  = sq * (1.f / 128.f) - mean * mean;
        float rstd = rsqrtf(var + EPSL);
        float p[5];
#pragma unroll
        for (int jj = 0; jj < 5; jj++)
          p[jj] = rstd * (d[jj] - mean * Gs[jj]) + Bs[jj];
        float psel = (l15 == 0) ? p[0] : (l15 == 1) ? p[1] :
                     (l15 == 2) ? p[2] : (l15 == 3) ? p[3] : p[4];
        if (l15 < 5) p_lds[wave][q & 1][toff][l15] = psel;
      }
      asm volatile("s_waitcnt lgkmcnt(0)" ::: "memory");   // wave-local
      // phase B: 32 serial RNN2/LN2/pool steps (group-local, 1 tanh/step)
      for (int s = 0; s < 32; s++) {
        float pv = p_lds[wave][q & 1][s][idx];
        float a = pv + t2_l;
#pragma unroll
        for (int jj = 0; jj < 5; jj++) a = fmaf(wrow[jj], h2rep[jj], a);
        float xn = tanh_fast(a);
        float s2 = dpp_sum16(xn * validf) * 0.2f;
        float dd = xn - s2;
        float v2 = dpp_sum16(dd * dd * validf) * 0.2f;
        float r2 = rsqrtf(v2 + EPSL);
        pool_l += dd * r2 * g2_l + be2_l;
        h2rep[0] = bcast16<0>(xn); h2rep[1] = bcast16<1>(xn);
        h2rep[2] = bcast16<2>(xn); h2rep[3] = bcast16<3>(xn);
        h2rep[4] = bcast16<4>(xn);
      }
    }
    float lg = pool_l * (1.f / 256.f);
    float mx = dpp_max16((l15 < 5) ? lg : -3.0e38f);
    float e  = (l15 < 5) ? __expf(lg - mx) : 0.f;
    float sm = dpp_sum16(e);
    if (q < 2 && l15 < 5)
      out[(size_t)(bt * 16 + row_l) * 5 + l15] = e / sm;
  }
}

// ============ rnn_tail_r11: fallback tail (R11, interleaved) ================
__global__ __launch_bounds__(256, 2)
void rnn_tail_r11(const unsigned short* __restrict__ hall,
                  const float* __restrict__ g1,  const float* __restrict__ be1,
                  const float* __restrict__ Wih2, const float* __restrict__ bih2,
                  const float* __restrict__ Whh2, const float* __restrict__ bhh2,
                  const float* __restrict__ g2,  const float* __restrict__ be2,
                  float* __restrict__ out)
{
  __shared__ float p_lds[4][4][8];
  const int tid  = threadIdx.x;
  const int wave = tid >> 6;
  const int lane = tid & 63;
  const int l15  = lane & 15;
  const int q    = lane >> 4;
  const int b    = blockIdx.x * 4 + wave;

  float w2g[5][8], Gs[5], Bs[5], wrow[5];
#pragma unroll
  for (int j = 0; j < 8; j++) {
    int c = l15 * 8 + j;
    float gc = g1[c];
#pragma unroll
    for (int jj = 0; jj < 5; jj++) w2g[jj][j] = Wih2[jj * DIM + c] * gc;
  }
#pragma unroll
  for (int jj = 0; jj < 5; jj++) { Gs[jj] = 0.f; Bs[jj] = 0.f; }
  for (int c = 0; c < DIM; c++) {
    float gc = g1[c], bc = be1[c];
#pragma unroll
    for (int jj = 0; jj < 5; jj++) {
      float w = Wih2[jj * DIM + c];
      Gs[jj] += w * gc; Bs[jj] += w * bc;
    }
  }
  const float validf = (l15 < 5) ? 1.f : 0.f;
  float t2_l = 0.f, g2_l = 0.f, be2_l = 0.f;
  if (l15 < 5) {
    t2_l = bih2[l15] + bhh2[l15];
    g2_l = g2[l15]; be2_l = be2[l15];
#pragma unroll
    for (int jj = 0; jj < 5; jj++) wrow[jj] = Whh2[l15 * 5 + jj];
  } else {
#pragma unroll
    for (int jj = 0; jj < 5; jj++) wrow[jj] = 0.f;
  }
  float h2rep[5];
#pragma unroll
  for (int jj = 0; jj < 5; jj++) h2rep[jj] = 0.f;
  float pool_l = 0.f;

  const unsigned short* hb = hall + (size_t)b * S_LEN * DIM;
  uint4 hpre = *(const uint4*)(hb + (size_t)q * DIM + l15 * 8);

  for (int t0 = 0; t0 < S_LEN; t0 += 4) {
    uint4 cur = hpre;
    if (t0 + 4 < S_LEN)
      hpre = *(const uint4*)(hb + (size_t)(t0 + 4 + q) * DIM + l15 * 8);
    float hv[8];
    hv[0] = __uint_as_float(cur.x << 16); hv[1] = __uint_as_float(cur.x & 0xffff0000u);
    hv[2] = __uint_as_float(cur.y << 16); hv[3] = __uint_as_float(cur.y & 0xffff0000u);
    hv[4] = __uint_as_float(cur.z << 16); hv[5] = __uint_as_float(cur.z & 0xffff0000u);
    hv[6] = __uint_as_float(cur.w << 16); hv[7] = __uint_as_float(cur.w & 0xffff0000u);
    float s = 0.f, sq = 0.f, d[5] = {0, 0, 0, 0, 0};
#pragma unroll
    for (int j = 0; j < 8; j++) {
      float v = hv[j];
      s += v; sq += v * v;
#pragma unroll
      for (int jj = 0; jj < 5; jj++) d[jj] = fmaf(w2g[jj][j], v, d[jj]);
    }
    red_level7<0x124>(s, sq, d);
    red_level7<0x128>(s, sq, d);
    red_level7<0x39>(s, sq, d);
    red_level7<0x4E>(s, sq, d);
    float mean = s * (1.f / 128.f);
    float var  = sq * (1.f / 128.f) - mean * mean;
    float rstd = rsqrtf(var + EPSL);
    float p[5];
#pragma unroll
    for (int jj = 0; jj < 5; jj++)
      p[jj] = rstd * (d[jj] - mean * Gs[jj]) + Bs[jj];
    float psel = (l15 == 0) ? p[0] : (l15 == 1) ? p[1] :
                 (l15 == 2) ? p[2] : (l15 == 3) ? p[3] : p[4];
    if (l15 < 5) p_lds[wave][q][l15] = psel;
    asm volatile("s_waitcnt lgkmcnt(0)" ::: "memory");
    const int idx = (l15 < 5) ? l15 : 0;
#pragma unroll
    for (int g = 0; g < 4; g++) {
      float pv = p_lds[wave][g][idx];
      float a = pv + t2_l;
#pragma unroll
      for (int jj = 0; jj < 5; jj++) a = fmaf(wrow[jj], h2rep[jj], a);
      float xn = tanh_fast(a);
      float s2 = dpp_sum16(xn * validf) * 0.2f;
      float dd = xn - s2;
      float v2 = dpp_sum16(dd * dd * validf) * 0.2f;
      float r2 = rsqrtf(v2 + EPSL);
      pool_l += dd * r2 * g2_l + be2_l;
      h2rep[0] = bcast16<0>(xn); h2rep[1] = bcast16<1>(xn);
      h2rep[2] = bcast16<2>(xn); h2rep[3] = bcast16<3>(xn);
      h2rep[4] = bcast16<4>(xn);
    }
  }

  float lg = pool_l * (1.f / 256.f);
  float mx = dpp_max16((l15 < 5) ? lg : -3.0e38f);
  float e  = (l15 < 5) ? __expf(lg - mx) : 0.f;
  float sm = dpp_sum16(e);
  if (q == 0 && l15 < 5) out[(size_t)b * 5 + l15] = e / sm;
}

extern "C" void kernel_launch(void* const* d_in, const int* in_sizes, int n_in,
                              void* d_out, int out_size, void* d_ws, size_t ws_size,
                              hipStream_t stream) {
  (void)in_sizes; (void)n_in; (void)out_size;
  const int*   x    = (const int*)  d_in[0];
  const float* emb  = (const float*)d_in[1];
  const float* Wih1 = (const float*)d_in[2];
  const float* bih1 = (const float*)d_in[3];
  const float* Whh1 = (const float*)d_in[4];
  const float* bhh1 = (const float*)d_in[5];
  const float* g1   = (const float*)d_in[6];
  const float* be1  = (const float*)d_in[7];
  const float* Wih2 = (const float*)d_in[8];
  const float* bih2 = (const float*)d_in[9];
  const float* Whh2 = (const float*)d_in[10];
  const float* bhh2 = (const float*)d_in[11];
  const float* g2   = (const float*)d_in[12];
  const float* be2  = (const float*)d_in[13];
  float* out = (float*)d_out;

  const size_t HBYTES = (size_t)1024 * S_LEN * DIM * 2;   // 64 MiB bf16 h
  unsigned short* hws = (unsigned short*)d_ws;

  if (ws_size >= HBYTES + 4096) {
    int* flags = (int*)((char*)d_ws + HBYTES);
    rnn_main<<<dim3(128), dim3(512), 0, stream>>>(
        x, emb, Wih1, bih1, Whh1, bhh1, g1, be1,
        Wih2, bih2, Whh2, bhh2, g2, be2, hws, flags, out);
  } else {
    // fallback: core-only mode (flags = nullptr) + R11 two-kernel tail
    rnn_main<<<dim3(64), dim3(512), 0, stream>>>(
        x, emb, Wih1, bih1, Whh1, bhh1, g1, be1,
        Wih2, bih2, Whh2, bhh2, g2, be2, hws, nullptr, out);
    rnn_tail_r11<<<dim3(256), dim3(256), 0, stream>>>(
        hws, g1, be1, Wih2, bih2, Whh2, bhh2, g2, be2, out);
  }
}